// Round 7
// baseline (185.448 us; speedup 1.0000x reference)
//
#include <hip/hip_runtime.h>
#include <hip/hip_bf16.h>
#include <math.h>

// InternImage DCNv3 block forward — round 32: stall-source fixes in sample_mlp.
// r31 post-mortem: occupancy 28.5->33.5% but dur 63.5->64.7 => NOT wave-
// starvation-limited; bound by per-block serial phase chain (L2/LDS stalls).
// Also: cross-round accounting shows ~82us fixed harness floor (2x ~41us
// workspace re-poison fills in the timed loop); controllable budget ~98us.
// This round:
//  1. cv[16][192] row stride 768B == 0 mod 128 -> phase-0 float4 writes hit
//     2/8 bank groups (~4x serialize; SQ_LDS_BANK_CONFLICT 1.47M).  Pad to
//     [16][196].  Same fix in ln_gemm8's new staging buffer.
//  2. T14 issue-early: phase-4 x residual (12 f32/thread) + phase-3 center xp
//     loads depend on nothing in-block -> issue at kernel entry, latency hides
//     under phases 0-3.
//  3. ln_gemm8 epilogue: 1536 scalar 2B stores -> LDS stage + 192x 16B stores.
// Config: sample 14px/896 blocks, ln_gemm 8px/1568, 3 launches, bf16
// intermediates, fragment-packed weights, XCD swizzles.

#define BATCH 4
#define HH 56
#define WW 56
#define CC 192
#define NPIX (BATCH * HH * WW)   // 12544
#define XS_STR 200               // 192+8 bf16 row stride
#define H1S 776                  // 768+8
#define OFS 193
#define MLS 97
#define CVS 196                  // padded cv row stride (float)
#define SPX 14                   // sample_mlp px/block
#define SBLK (NPIX / SPX)        // 896

typedef __hip_bfloat16 bf16;
typedef __attribute__((ext_vector_type(8))) short short8;
typedef __attribute__((ext_vector_type(4))) float float4v;

__device__ __forceinline__ float gelu_exact(float x) {
    return 0.5f * x * (1.f + erff(x * 0.70710678118654752f));
}
__device__ __forceinline__ bf16 f2b(float f) { return __float2bfloat16(f); }
__device__ __forceinline__ float b2fu(short s) {
    return __uint_as_float((unsigned)(unsigned short)s << 16);
}

// ---- weight prep: pack to MFMA fragment order ------------------------------
// omP 19 tiles: 12 off (192 cols) + 6 mask (96 cols) + 1 cfs (12 cols+pad)
__global__ __launch_bounds__(256) void prep_w_k(const float* __restrict__ inpw,
        const float* __restrict__ offw, const float* __restrict__ maskw,
        const float* __restrict__ cfsw, const float* __restrict__ outpw,
        const float* __restrict__ fc1w, const float* __restrict__ fc2w,
        bf16* __restrict__ wsB)
{
    const int i = blockIdx.x * 256 + threadIdx.x;
    bf16* inpP = wsB;
    bf16* omP  = wsB + 36864;
    bf16* outP = wsB + 95232;
    bf16* fc1P = wsB + 132096;
    bf16* fc2P = wsB + 279552;
    const int j   = i & 7;
    const int l   = (i >> 3) & 63;
    const int n15 = l & 15, q = l >> 4;
    const int grp = i >> 9;
    if (i < 36864) {
        const int t = grp / 6, c = grp - t * 6;
        const int n = 16 * t + n15, k = 32 * c + 8 * q + j;
        inpP[i] = f2b(inpw[(size_t)k * 192 + n]);
        outP[i] = f2b(outpw[(size_t)k * 192 + n]);
    }
    if (i < 58368) {
        const int t = grp / 6, c = grp - t * 6;
        const int n = 16 * t + n15, k = 32 * c + 8 * q + j;
        omP[i] = (n < 192) ? f2b(offw[(size_t)k * 192 + n])
               : (n < 288) ? f2b(maskw[(size_t)k * 96 + (n - 192)])
               : (n < 300) ? f2b(cfsw[(size_t)(n - 288) * 192 + k])
                           : f2b(0.f);
    }
    if (i < 147456) {
        const int t1 = grp / 6, c1 = grp - t1 * 6;
        const int n1 = 16 * t1 + n15, k1 = 32 * c1 + 8 * q + j;
        fc1P[i] = f2b(fc1w[(size_t)k1 * 768 + n1]);
        const int t2 = grp / 24, c2 = grp - t2 * 24;
        const int n2 = 16 * t2 + n15, k2 = 32 * c2 + 8 * q + j;
        fc2P[i] = f2b(fc2w[(size_t)k2 * 192 + n2]);
    }
}

// ==== FUSED: LN(x, norm1) + in_proj MFMA, 8 px/block (1568 blocks) ===========
__global__ __launch_bounds__(256) void ln_gemm8_k(const float* __restrict__ x,
        const float* __restrict__ n1w, const float* __restrict__ n1b,
        const bf16* __restrict__ wP, const float* __restrict__ bias,
        bf16* __restrict__ xn_out, bf16* __restrict__ xp_out)
{
    __shared__ __align__(16) bf16 xs[8 * XS_STR];
    __shared__ __align__(16) bf16 xs2[8 * XS_STR];   // xp staging (padded rows)
    const int tid = threadIdx.x;
    const int w   = tid >> 6;
    const int l   = tid & 63;
    const int n15 = l & 15;
    const int q   = l >> 4;
    const int p0  = blockIdx.x * 8;
    const int c0  = l * 4;

    #pragma unroll
    for (int rr = 0; rr < 2; rr++) {
        const int lr = 2 * w + rr;
        const int base = (p0 + lr) * CC;
        float4 v = (float4){0.f, 0.f, 0.f, 0.f};
        if (l < 48) v = *(const float4*)&x[base + c0];
        float s  = v.x + v.y + v.z + v.w;
        float qq = v.x*v.x + v.y*v.y + v.z*v.z + v.w*v.w;
        #pragma unroll
        for (int off = 32; off > 0; off >>= 1) {
            s  += __shfl_xor(s, off, 64);
            qq += __shfl_xor(qq, off, 64);
        }
        const float mu  = s * (1.f / CC);
        const float var = qq * (1.f / CC) - mu * mu;
        const float rs  = rsqrtf(var + 1e-5f);
        if (l < 48) {
            const float4 nw = *(const float4*)&n1w[c0];
            const float4 nb = *(const float4*)&n1b[c0];
            ushort4 u;
            bf16 h;
            h = f2b((v.x - mu) * rs * nw.x + nb.x); u.x = *(unsigned short*)&h;
            h = f2b((v.y - mu) * rs * nw.y + nb.y); u.y = *(unsigned short*)&h;
            h = f2b((v.z - mu) * rs * nw.z + nb.z); u.z = *(unsigned short*)&h;
            h = f2b((v.w - mu) * rs * nw.w + nb.w); u.w = *(unsigned short*)&h;
            *(ushort4*)&xs[lr * XS_STR + c0] = u;
            *(ushort4*)&xn_out[base + c0] = u;
        }
    }
    __syncthreads();

    short8 aF[6];
    #pragma unroll
    for (int c = 0; c < 6; c++)
        aF[c] = (n15 < 8)
              ? *(const short8*)&xs[n15 * XS_STR + c * 32 + q * 8]
              : (short8){0, 0, 0, 0, 0, 0, 0, 0};

    for (int t = w; t < 12; t += 4) {        // 12 tiles = 192 cols
        float4v acc = (float4v){0.f, 0.f, 0.f, 0.f};
        #pragma unroll
        for (int c = 0; c < 6; c++) {
            const short8 bF = *(const short8*)&wP[(size_t)((t * 6 + c) * 64 + l) * 8];
            acc = __builtin_amdgcn_mfma_f32_16x16x32_bf16(aF[c], bF, acc, 0, 0, 0);
        }
        if (q < 2) {
            const int n0 = 16 * t;
            const float bb = bias[n0 + n15];
            #pragma unroll
            for (int r = 0; r < 4; r++)
                xs2[(4 * q + r) * XS_STR + n0 + n15] = f2b(acc[r] + bb);
        }
    }
    __syncthreads();

    // coalesced 16B stores of the staged xp tile
    if (tid < 192) {
        const int row = tid / 24, c8 = tid - row * 24;
        *(short8*)&xp_out[(size_t)(p0 + row) * CC + c8 * 8] =
            *(const short8*)&xs2[row * XS_STR + c8 * 8];
    }
}

// ==== MEGA-FUSED: dwconv+LN+GELU + off/mask/cfs MFMA + softmax + bilinear
//      sampling + cfs blend (-> LDS) + out_proj + LN(rpn1)+res + LN(norm2)
//      + fc1+GELU + fc2 + LN(rpn2) + res.   14 px/block, 896 blocks.
__global__ __launch_bounds__(256) void sample_mlp_k(
        const bf16* __restrict__ xp, const bf16* __restrict__ xn,
        const float* __restrict__ dww, const float* __restrict__ dwb,
        const float* __restrict__ dwlnw, const float* __restrict__ dwlnb,
        const bf16* __restrict__ omP, const float* __restrict__ offb,
        const float* __restrict__ maskb, const float* __restrict__ cfsb,
        const bf16* __restrict__ wP, const float* __restrict__ bias,
        const float* __restrict__ x,
        const float* __restrict__ r1w, const float* __restrict__ r1b,
        const float* __restrict__ n2w, const float* __restrict__ n2b,
        const bf16* __restrict__ fc1P, const float* __restrict__ fc1b,
        const bf16* __restrict__ fc2P, const float* __restrict__ fc2b,
        const float* __restrict__ r2w, const float* __restrict__ r2b,
        float* __restrict__ out)
{
    __shared__ __align__(16) bf16 xs[16 * XS_STR];
    // union region, disjoint lifetimes (16-row sized for pad-row safety):
    //   phase 0-1: cv[16][196] f32 (12544 B, padded stride vs bank conflicts)
    //   phase 2-3: offs_l[16][193] (12352) + mls_l[16][97] (6208) + cfs[16][16]
    //   phase 4+ : h1[16][H1S] bf16 (24832 B)
    __shared__ __align__(16) char uni[16 * H1S * 2];
    __shared__ float ps[4][16], pq[4][16], ps2[4][16], pq2[4][16];

    float (*cv)[CVS]     = (float(*)[CVS])uni;
    float (*offs_l)[OFS] = (float(*)[OFS])uni;
    float (*mls_l)[MLS]  = (float(*)[MLS])(uni + 12352);
    float (*cfs_l)[16]   = (float(*)[16])(uni + 18560);
    bf16* h1             = (bf16*)uni;

    const int tid = threadIdx.x;
    const int w   = tid >> 6;
    const int l   = tid & 63;
    const int n15 = l & 15;
    const int q   = l >> 4;
    const int bid = (blockIdx.x & 7) * (SBLK / 8) + (blockIdx.x >> 3);
    const int p0  = bid * SPX;

    // ---- T14 issue-early prefetches (depend on nothing computed in-block) --
    // (a) phase-4 residual x rows: 12 f32/thread
    float xpre[3][4];
    #pragma unroll
    for (int r = 0; r < 4; r++) {
        const int growc = min(p0 + 4 * q + r, NPIX - 1);
        #pragma unroll
        for (int t = 0; t < 3; t++)
            xpre[t][r] = x[(size_t)growc * CC + 48 * w + 16 * t + n15];
    }
    // (b) phase-0/3 item geometry + phase-3 center xp loads
    const bool samp = tid < SPX * 12;
    const int s_px  = tid / 12;
    const int s_g   = tid - s_px * 12;
    const int s_ch0 = s_g * 16;
    const int s_pix = min(p0 + s_px, NPIX - 1);
    const int s_bim = s_pix / (HH * WW);
    const int s_hw  = s_pix - s_bim * (HH * WW);
    const int s_h   = s_hw / WW;
    const int s_wxp = s_hw - s_h * WW;
    const int s_ib  = s_bim * (HH * WW * CC);
    short8 xv0p = {0,0,0,0,0,0,0,0}, xv1p = {0,0,0,0,0,0,0,0};
    if (samp) {
        const int po = s_pix * CC + s_ch0;
        xv0p = *(const short8*)&xp[po];
        xv1p = *(const short8*)&xp[po + 8];
    }

    // ---- phase 0: depthwise 3x3 conv, 16ch/item, 14*12=168 items, ONE pass -
    if (samp) {
        float a[16];
        #pragma unroll
        for (int j = 0; j < 16; j += 4) {
            const float4 b4 = *(const float4*)&dwb[s_ch0 + j];
            a[j] = b4.x; a[j+1] = b4.y; a[j+2] = b4.z; a[j+3] = b4.w;
        }
        #pragma unroll
        for (int ky = 0; ky < 3; ky++) {
            const int yy = s_h + ky - 1;
            if (yy < 0 || yy >= HH) continue;
            #pragma unroll
            for (int kx = 0; kx < 3; kx++) {
                const int xx = s_wxp + kx - 1;
                if (xx < 0 || xx >= WW) continue;
                const int o = s_ib + (yy * WW + xx) * CC + s_ch0;
                const short8 v0 = *(const short8*)&xn[o];
                const short8 v1 = *(const short8*)&xn[o + 8];
                const int wo = (ky * 3 + kx) * CC + s_ch0;
                const float4 w0 = *(const float4*)&dww[wo];
                const float4 w1 = *(const float4*)&dww[wo + 4];
                const float4 w2 = *(const float4*)&dww[wo + 8];
                const float4 w3 = *(const float4*)&dww[wo + 12];
                a[0]  += b2fu(v0[0]) * w0.x; a[1]  += b2fu(v0[1]) * w0.y;
                a[2]  += b2fu(v0[2]) * w0.z; a[3]  += b2fu(v0[3]) * w0.w;
                a[4]  += b2fu(v0[4]) * w1.x; a[5]  += b2fu(v0[5]) * w1.y;
                a[6]  += b2fu(v0[6]) * w1.z; a[7]  += b2fu(v0[7]) * w1.w;
                a[8]  += b2fu(v1[0]) * w2.x; a[9]  += b2fu(v1[1]) * w2.y;
                a[10] += b2fu(v1[2]) * w2.z; a[11] += b2fu(v1[3]) * w2.w;
                a[12] += b2fu(v1[4]) * w3.x; a[13] += b2fu(v1[5]) * w3.y;
                a[14] += b2fu(v1[6]) * w3.z; a[15] += b2fu(v1[7]) * w3.w;
            }
        }
        #pragma unroll
        for (int j = 0; j < 16; j += 4)
            *(float4*)&cv[s_px][s_ch0 + j] = (float4){a[j], a[j+1], a[j+2], a[j+3]};
    }
    __syncthreads();

    // ---- phase 1: LN(1e-6) + GELU -> xs fragments (wave w -> px w+4*pass) --
    #pragma unroll
    for (int pass = 0; pass < 4; pass++) {
        const int px = w + 4 * pass;
        if (px >= SPX) break;
        float v[3];
        #pragma unroll
        for (int i = 0; i < 3; i++) v[i] = cv[px][l + 64 * i];
        float s = v[0] + v[1] + v[2];
        float qq = v[0]*v[0] + v[1]*v[1] + v[2]*v[2];
        #pragma unroll
        for (int off = 32; off > 0; off >>= 1) {
            s  += __shfl_xor(s, off, 64);
            qq += __shfl_xor(qq, off, 64);
        }
        const float mu  = s * (1.f / CC);
        const float var = qq * (1.f / CC) - mu * mu;
        const float rs  = rsqrtf(var + 1e-6f);
        #pragma unroll
        for (int i = 0; i < 3; i++) {
            const int c = l + 64 * i;
            xs[px * XS_STR + c] = f2b(gelu_exact((v[i] - mu) * rs * dwlnw[c] + dwlnb[c]));
        }
    }
    __syncthreads();

    // ---- phase 2: off/mask/cfs MFMA (19 tiles) + epilogues -----------------
    // A rows 14/15 stale: MFMA row-containment keeps them in C rows 14/15,
    // never read by phase 3 (px<14).
    {
        short8 aF[6];
        #pragma unroll
        for (int c = 0; c < 6; c++)
            aF[c] = *(const short8*)&xs[n15 * XS_STR + c * 32 + q * 8];

        for (int t = w; t < 19; t += 4) {
            float4v acc = (float4v){0.f, 0.f, 0.f, 0.f};
            #pragma unroll
            for (int c = 0; c < 6; c++) {
                const short8 bF = *(const short8*)&omP[(size_t)((t * 6 + c) * 64 + l) * 8];
                acc = __builtin_amdgcn_mfma_f32_16x16x32_bf16(aF[c], bF, acc, 0, 0, 0);
            }
            if (t < 12) {
                const int n0 = 16 * t;
                const float bb = offb[n0 + n15];
                #pragma unroll
                for (int r = 0; r < 4; r++)
                    offs_l[4 * q + r][n0 + n15] = acc[r] + bb;
            } else if (t < 18) {
                const int m0 = 16 * t - 192;
                const float bb = maskb[m0 + n15];
                #pragma unroll
                for (int r = 0; r < 4; r++) {
                    const float vv = acc[r] + bb;
                    float mx = vv;
                    mx = fmaxf(mx, __shfl_xor(mx, 1, 64));
                    mx = fmaxf(mx, __shfl_xor(mx, 2, 64));
                    mx = fmaxf(mx, __shfl_xor(mx, 4, 64));
                    const float e = __expf(vv - mx);
                    float se = e;
                    se += __shfl_xor(se, 1, 64);
                    se += __shfl_xor(se, 2, 64);
                    se += __shfl_xor(se, 4, 64);
                    mls_l[4 * q + r][m0 + n15] = e * (1.f / se);
                }
            } else {
                const float bb = (n15 < 12) ? cfsb[n15] : 0.f;
                #pragma unroll
                for (int r = 0; r < 4; r++) {
                    const float cf = 1.f / (1.f + __expf(-(acc[r] + bb)));
                    if (n15 < 12) cfs_l[4 * q + r][n15] = cf;
                }
            }
        }
    }
    __syncthreads();

    // ---- phase 3: bilinear sampling + cfs blend -> xs, 168 items x 16ch ----
    if (samp) {
        const float cf = cfs_l[s_px][s_g];

        float acc[16];
        #pragma unroll
        for (int j = 0; j < 16; j++) acc[j] = 0.f;

        #pragma unroll 2
        for (int k = 0; k < 8; k++) {
            // grid point (remove_center): kk = k + (k>=4); gx = kk/3-1, gy = kk%3-1
            const int kk = k + (k >= 4 ? 1 : 0);
            const int gx = kk / 3 - 1;
            const int gy = kk - (kk / 3) * 3 - 1;
            const float mk  = mls_l[s_px][s_g * 8 + k];
            const float px_ = (float)(s_wxp + gx) + offs_l[s_px][s_g * 16 + 2 * k];
            const float py_ = (float)(s_h   + gy) + offs_l[s_px][s_g * 16 + 2 * k + 1];
            const float fx = floorf(px_), fy = floorf(py_);
            const float wxf = px_ - fx, wyf = py_ - fy;
            const int x0 = (int)fx, y0 = (int)fy;
            const float vx0 = ((unsigned)x0       < WW) ? 1.f : 0.f;
            const float vx1 = ((unsigned)(x0 + 1) < WW) ? 1.f : 0.f;
            const float vy0 = ((unsigned)y0       < HH) ? 1.f : 0.f;
            const float vy1 = ((unsigned)(y0 + 1) < HH) ? 1.f : 0.f;
            const int x0c = min(max(x0, 0), WW - 1);
            const int x1c = min(max(x0 + 1, 0), WW - 1);
            const int y0c = min(max(y0, 0), HH - 1);
            const int y1c = min(max(y0 + 1, 0), HH - 1);
            const float wx0 = (1.f - wxf) * vx0, wx1 = wxf * vx1;
            const float wy0 = (1.f - wyf) * vy0, wy1 = wyf * vy1;
            const float w00 = mk * wy0 * wx0, w01 = mk * wy0 * wx1;
            const float w10 = mk * wy1 * wx0, w11 = mk * wy1 * wx1;
            const int r0 = s_ib + y0c * (WW * CC) + s_ch0;
            const int r1 = s_ib + y1c * (WW * CC) + s_ch0;
            const int o00 = r0 + x0c * CC, o01 = r0 + x1c * CC;
            const int o10 = r1 + x0c * CC, o11 = r1 + x1c * CC;
            const short8 a00 = *(const short8*)&xp[o00];
            const short8 b00 = *(const short8*)&xp[o00 + 8];
            const short8 a01 = *(const short8*)&xp[o01];
            const short8 b01 = *(const short8*)&xp[o01 + 8];
            const short8 a10 = *(const short8*)&xp[o10];
            const short8 b10 = *(const short8*)&xp[o10 + 8];
            const short8 a11 = *(const short8*)&xp[o11];
            const short8 b11 = *(const short8*)&xp[o11 + 8];
            #pragma unroll
            for (int j = 0; j < 8; j++) {
                acc[j]     += w00 * b2fu(a00[j]) + w01 * b2fu(a01[j])
                            + w10 * b2fu(a10[j]) + w11 * b2fu(a11[j]);
                acc[8 + j] += w00 * b2fu(b00[j]) + w01 * b2fu(b01[j])
                            + w10 * b2fu(b10[j]) + w11 * b2fu(b11[j]);
            }
        }

        short8 o0, o1;
        #pragma unroll
        for (int j = 0; j < 8; j++) {
            const float v0 = acc[j]     * (1.f - cf) + b2fu(xv0p[j]) * cf;
            const float v1 = acc[8 + j] * (1.f - cf) + b2fu(xv1p[j]) * cf;
            bf16 hh;
            hh = f2b(v0); o0[j] = *(short*)&hh;
            hh = f2b(v1); o1[j] = *(short*)&hh;
        }
        *(short8*)&xs[s_px * XS_STR + s_ch0]     = o0;  // blended tile in LDS
        *(short8*)&xs[s_px * XS_STR + s_ch0 + 8] = o1;
    }
    __syncthreads();

    // ---- phase 4: out_proj MFMA + LN(rpn1)+res + LN(norm2) + fc1/gelu + fc2
    //      + LN(rpn2) + res.  Pad rows: loads clamped, stores guarded. -------
    {
        short8 aF[6];
        #pragma unroll
        for (int c = 0; c < 6; c++)
            aF[c] = *(const short8*)&xs[n15 * XS_STR + c * 32 + q * 8];

        float4v acc[3];
        #pragma unroll
        for (int t = 0; t < 3; t++) {
            const int tile = 3 * w + t;
            acc[t] = (float4v){0.f, 0.f, 0.f, 0.f};
            #pragma unroll
            for (int c = 0; c < 6; c++) {
                const short8 bF = *(const short8*)&wP[(size_t)((tile * 6 + c) * 64 + l) * 8];
                acc[t] = __builtin_amdgcn_mfma_f32_16x16x32_bf16(aF[c], bF, acc[t], 0, 0, 0);
            }
            const float bb = bias[16 * tile + n15];
            #pragma unroll
            for (int r = 0; r < 4; r++) acc[t][r] += bb;
        }

        #pragma unroll
        for (int r = 0; r < 4; r++) {
            float sp = acc[0][r] + acc[1][r] + acc[2][r];
            float qp = acc[0][r]*acc[0][r] + acc[1][r]*acc[1][r] + acc[2][r]*acc[2][r];
            #pragma unroll
            for (int o = 1; o < 16; o <<= 1) {
                sp += __shfl_xor(sp, o, 64);
                qp += __shfl_xor(qp, o, 64);
            }
            if (n15 == 0) { ps[w][4 * q + r] = sp; pq[w][4 * q + r] = qp; }
        }
        __syncthreads();

        float x2v[3][4];
        #pragma unroll
        for (int r = 0; r < 4; r++) {
            const int row = 4 * q + r;
            const float s  = ps[0][row] + ps[1][row] + ps[2][row] + ps[3][row];
            const float qq = pq[0][row] + pq[1][row] + pq[2][row] + pq[3][row];
            const float mu  = s * (1.f / CC);
            const float var = qq * (1.f / CC) - mu * mu;
            const float rs  = rsqrtf(var + 1e-5f);
            #pragma unroll
            for (int t = 0; t < 3; t++) {
                const int col = 48 * w + 16 * t + n15;
                x2v[t][r] = xpre[t][r] + (acc[t][r] - mu) * rs * r1w[col] + r1b[col];
            }
        }
        #pragma unroll
        for (int r = 0; r < 4; r++) {
            float sp = x2v[0][r] + x2v[1][r] + x2v[2][r];
            float qp = x2v[0][r]*x2v[0][r] + x2v[1][r]*x2v[1][r] + x2v[2][r]*x2v[2][r];
            #pragma unroll
            for (int o = 1; o < 16; o <<= 1) {
                sp += __shfl_xor(sp, o, 64);
                qp += __shfl_xor(qp, o, 64);
            }
            if (n15 == 0) { ps2[w][4 * q + r] = sp; pq2[w][4 * q + r] = qp; }
        }
        __syncthreads();

        #pragma unroll
        for (int r = 0; r < 4; r++) {
            const int row = 4 * q + r;
            const float s  = ps2[0][row] + ps2[1][row] + ps2[2][row] + ps2[3][row];
            const float qq = pq2[0][row] + pq2[1][row] + pq2[2][row] + pq2[3][row];
            const float mu  = s * (1.f / CC);
            const float var = qq * (1.f / CC) - mu * mu;
            const float rs  = rsqrtf(var + 1e-5f);
            #pragma unroll
            for (int t = 0; t < 3; t++) {
                const int col = 48 * w + 16 * t + n15;
                xs[row * XS_STR + col] = f2b((x2v[t][r] - mu) * rs * n2w[col] + n2b[col]);
            }
        }
        __syncthreads();

        short8 aF2[6];
        #pragma unroll
        for (int c = 0; c < 6; c++)
            aF2[c] = *(const short8*)&xs[n15 * XS_STR + c * 32 + q * 8];

        #pragma unroll
        for (int t1 = 0; t1 < 12; t1++) {
            const int tile = 12 * w + t1;
            float4v a1 = (float4v){0.f, 0.f, 0.f, 0.f};
            #pragma unroll
            for (int c = 0; c < 6; c++) {
                const short8 bF = *(const short8*)&fc1P[(size_t)((tile * 6 + c) * 64 + l) * 8];
                a1 = __builtin_amdgcn_mfma_f32_16x16x32_bf16(aF2[c], bF, a1, 0, 0, 0);
            }
            const int n0 = 16 * tile;
            const float bb = fc1b[n0 + n15];
            #pragma unroll
            for (int r = 0; r < 4; r++)
                h1[(4 * q + r) * H1S + n0 + n15] = f2b(gelu_exact(a1[r] + bb));
        }
        __syncthreads();

        float4v acc2[3];
        #pragma unroll
        for (int t = 0; t < 3; t++) acc2[t] = (float4v){0.f, 0.f, 0.f, 0.f};
        #pragma unroll 4
        for (int kc = 0; kc < 24; kc++) {
            const short8 a2 = *(const short8*)&h1[n15 * H1S + kc * 32 + q * 8];
            #pragma unroll
            for (int t = 0; t < 3; t++) {
                const int tile = 3 * w + t;
                const short8 bF = *(const short8*)&fc2P[(size_t)((tile * 24 + kc) * 64 + l) * 8];
                acc2[t] = __builtin_amdgcn_mfma_f32_16x16x32_bf16(a2, bF, acc2[t], 0, 0, 0);
            }
        }
        #pragma unroll
        for (int t = 0; t < 3; t++) {
            const float bb = fc2b[48 * w + 16 * t + n15];
            #pragma unroll
            for (int r = 0; r < 4; r++) acc2[t][r] += bb;
        }

        #pragma unroll
        for (int r = 0; r < 4; r++) {
            float sp = acc2[0][r] + acc2[1][r] + acc2[2][r];
            float qp = acc2[0][r]*acc2[0][r] + acc2[1][r]*acc2[1][r] + acc2[2][r]*acc2[2][r];
            #pragma unroll
            for (int o = 1; o < 16; o <<= 1) {
                sp += __shfl_xor(sp, o, 64);
                qp += __shfl_xor(qp, o, 64);
            }
            if (n15 == 0) { ps[w][4 * q + r] = sp; pq[w][4 * q + r] = qp; }
        }
        __syncthreads();

        #pragma unroll
        for (int r = 0; r < 4; r++) {
            const int row = 4 * q + r;
            if (row >= SPX) continue;                   // pad rows alias next block!
            const float s  = ps[0][row] + ps[1][row] + ps[2][row] + ps[3][row];
            const float qq = pq[0][row] + pq[1][row] + pq[2][row] + pq[3][row];
            const float mu  = s * (1.f / CC);
            const float var = qq * (1.f / CC) - mu * mu;
            const float rs  = rsqrtf(var + 1e-5f);
            const size_t grow = p0 + row;
            #pragma unroll
            for (int t = 0; t < 3; t++) {
                const int col = 48 * w + 16 * t + n15;
                out[grow * CC + col] = x2v[t][r]
                                     + (acc2[t][r] - mu) * rs * r2w[col] + r2b[col];
            }
        }
    }
}

extern "C" void kernel_launch(void* const* d_in, const int* in_sizes, int n_in,
                              void* d_out, int out_size, void* d_ws, size_t ws_size,
                              hipStream_t stream) {
    const float* x      = (const float*)d_in[0];
    const float* n1w    = (const float*)d_in[1];
    const float* n1b    = (const float*)d_in[2];
    const float* n2w    = (const float*)d_in[3];
    const float* n2b    = (const float*)d_in[4];
    const float* rpn1w  = (const float*)d_in[5];
    const float* rpn1b  = (const float*)d_in[6];
    const float* rpn2w  = (const float*)d_in[7];
    const float* rpn2b  = (const float*)d_in[8];
    const float* inpw   = (const float*)d_in[9];
    const float* inpb   = (const float*)d_in[10];
    const float* dww    = (const float*)d_in[11];
    const float* dwb    = (const float*)d_in[12];
    const float* dwlnw  = (const float*)d_in[13];
    const float* dwlnb  = (const float*)d_in[14];
    const float* offw   = (const float*)d_in[15];
    const float* offb   = (const float*)d_in[16];
    const float* maskw  = (const float*)d_in[17];
    const float* maskb  = (const float*)d_in[18];
    const float* cfsw   = (const float*)d_in[19];
    const float* cfsb   = (const float*)d_in[20];
    const float* outpw  = (const float*)d_in[21];
    const float* outpb  = (const float*)d_in[22];
    const float* fc1w   = (const float*)d_in[23];
    const float* fc1b   = (const float*)d_in[24];
    const float* fc2w   = (const float*)d_in[25];
    const float* fc2b   = (const float*)d_in[26];

    const int N = NPIX;                       // 12544
    const size_t NP = (size_t)N * CC;
    bf16* B0  = (bf16*)d_ws;                  // xn
    bf16* B1  = B0 + NP;                      // xp
    bf16* wsB = B1 + NP;                      // packed bf16 weights
    const bf16* inpP = wsB;
    const bf16* omP  = wsB + 36864;           // 19 tiles (off+mask+cfs)
    const bf16* outP = wsB + 95232;
    const bf16* fc1P = wsB + 132096;
    const bf16* fc2P = wsB + 279552;

    // 0. weight prep (bf16, fragment-packed; cfs_w folded into om pack)
    prep_w_k<<<576, 256, 0, stream>>>(inpw, offw, maskw, cfsw, outpw, fc1w, fc2w, wsB);
    // 1. FUSED xn = LN(x); xp = xn @ in_proj + b   (8px, 1568 blocks) -> B0, B1
    ln_gemm8_k<<<N / 8, 256, 0, stream>>>(x, n1w, n1b, inpP, inpb, B0, B1);
    // 2. MEGA-FUSED dwconv+off/mask GEMM+sampling+blend+out_proj+MLP (14px) -> d_out
    sample_mlp_k<<<SBLK, 256, 0, stream>>>(B1, B0, dww, dwb, dwlnw, dwlnb,
                                           omP, offb, maskb, cfsb,
                                           outP, outpb, x, rpn1w, rpn1b,
                                           n2w, n2b, fc1P, fc1b, fc2P, fc2b,
                                           rpn2w, rpn2b, (float*)d_out);
}

// Round 10
// 179.787 us; speedup vs baseline: 1.0315x; 1.0315x over previous
//
#include <hip/hip_runtime.h>
#include <hip/hip_bf16.h>
#include <math.h>

// InternImage DCNv3 block forward — round 35: recombine measured-best configs.
// r33/r34 post-mortem: cooperative merge failed twice; r34's absmax 8.69 ~=
// max|ref| => output all zeros => hipLaunchCooperativeKernel almost certainly
// rejected under graph capture (error was swallowed).  A runtime fallback is
// unsafe (failed call during capture invalidates the capture).  Abandoning
// coop; expected gain (~15us) not worth a third strike.
// r31's A/B decomposes: sample_mlp 16px (r28, 63.5us) beats 14px (r31,
// 64.7us) -- weight streaming (784 vs 896 blocks) dominates occupancy for
// this latency-bound kernel; ln_gemm 8px (r31) was the net-positive piece
// (+1.3us).  This round: sample_mlp_k @16px (r28 verbatim) + ln_gemm8_k @8px
// (r31 verbatim) + prep_w_k, 3 plain launches.
// Config: bf16 intermediates, fragment-packed weights (19-tile off/mask/cfs
// pack), XCD swizzles.  ws: B0 (xn), B1 (xp) | packed weights.

#define BATCH 4
#define HH 56
#define WW 56
#define CC 192
#define NPIX (BATCH * HH * WW)   // 12544
#define XS_STR 200               // 192+8 bf16 row stride
#define H1S 776                  // 768+8
#define OFS 193
#define MLS 97

typedef __hip_bfloat16 bf16;
typedef __attribute__((ext_vector_type(8))) short short8;
typedef __attribute__((ext_vector_type(4))) float float4v;

__device__ __forceinline__ float gelu_exact(float x) {
    return 0.5f * x * (1.f + erff(x * 0.70710678118654752f));
}
__device__ __forceinline__ bf16 f2b(float f) { return __float2bfloat16(f); }
__device__ __forceinline__ float b2fu(short s) {
    return __uint_as_float((unsigned)(unsigned short)s << 16);
}

// ---- weight prep: pack to MFMA fragment order ------------------------------
// omP 19 tiles: 12 off (192 cols) + 6 mask (96 cols) + 1 cfs (12 cols+pad)
__global__ __launch_bounds__(256) void prep_w_k(const float* __restrict__ inpw,
        const float* __restrict__ offw, const float* __restrict__ maskw,
        const float* __restrict__ cfsw, const float* __restrict__ outpw,
        const float* __restrict__ fc1w, const float* __restrict__ fc2w,
        bf16* __restrict__ wsB)
{
    const int i = blockIdx.x * 256 + threadIdx.x;
    bf16* inpP = wsB;
    bf16* omP  = wsB + 36864;
    bf16* outP = wsB + 95232;
    bf16* fc1P = wsB + 132096;
    bf16* fc2P = wsB + 279552;
    const int j   = i & 7;
    const int l   = (i >> 3) & 63;
    const int n15 = l & 15, q = l >> 4;
    const int grp = i >> 9;
    if (i < 36864) {
        const int t = grp / 6, c = grp - t * 6;
        const int n = 16 * t + n15, k = 32 * c + 8 * q + j;
        inpP[i] = f2b(inpw[(size_t)k * 192 + n]);
        outP[i] = f2b(outpw[(size_t)k * 192 + n]);
    }
    if (i < 58368) {
        const int t = grp / 6, c = grp - t * 6;
        const int n = 16 * t + n15, k = 32 * c + 8 * q + j;
        omP[i] = (n < 192) ? f2b(offw[(size_t)k * 192 + n])
               : (n < 288) ? f2b(maskw[(size_t)k * 96 + (n - 192)])
               : (n < 300) ? f2b(cfsw[(size_t)(n - 288) * 192 + k])
                           : f2b(0.f);
    }
    if (i < 147456) {
        const int t1 = grp / 6, c1 = grp - t1 * 6;
        const int n1 = 16 * t1 + n15, k1 = 32 * c1 + 8 * q + j;
        fc1P[i] = f2b(fc1w[(size_t)k1 * 768 + n1]);
        const int t2 = grp / 24, c2 = grp - t2 * 24;
        const int n2 = 16 * t2 + n15, k2 = 32 * c2 + 8 * q + j;
        fc2P[i] = f2b(fc2w[(size_t)k2 * 192 + n2]);
    }
}

// ==== FUSED: LN(x, norm1) + in_proj MFMA, 8 px/block (1568 blocks) ===========
__global__ __launch_bounds__(256) void ln_gemm8_k(const float* __restrict__ x,
        const float* __restrict__ n1w, const float* __restrict__ n1b,
        const bf16* __restrict__ wP, const float* __restrict__ bias,
        bf16* __restrict__ xn_out, bf16* __restrict__ xp_out)
{
    __shared__ __align__(16) bf16 xs[8 * XS_STR];
    const int tid = threadIdx.x;
    const int w   = tid >> 6;
    const int l   = tid & 63;
    const int n15 = l & 15;
    const int q   = l >> 4;
    const int p0  = blockIdx.x * 8;
    const int c0  = l * 4;

    #pragma unroll
    for (int rr = 0; rr < 2; rr++) {
        const int lr = 2 * w + rr;
        const int base = (p0 + lr) * CC;
        float4 v = (float4){0.f, 0.f, 0.f, 0.f};
        if (l < 48) v = *(const float4*)&x[base + c0];
        float s  = v.x + v.y + v.z + v.w;
        float qq = v.x*v.x + v.y*v.y + v.z*v.z + v.w*v.w;
        #pragma unroll
        for (int off = 32; off > 0; off >>= 1) {
            s  += __shfl_xor(s, off, 64);
            qq += __shfl_xor(qq, off, 64);
        }
        const float mu  = s * (1.f / CC);
        const float var = qq * (1.f / CC) - mu * mu;
        const float rs  = rsqrtf(var + 1e-5f);
        if (l < 48) {
            const float4 nw = *(const float4*)&n1w[c0];
            const float4 nb = *(const float4*)&n1b[c0];
            ushort4 u;
            bf16 h;
            h = f2b((v.x - mu) * rs * nw.x + nb.x); u.x = *(unsigned short*)&h;
            h = f2b((v.y - mu) * rs * nw.y + nb.y); u.y = *(unsigned short*)&h;
            h = f2b((v.z - mu) * rs * nw.z + nb.z); u.z = *(unsigned short*)&h;
            h = f2b((v.w - mu) * rs * nw.w + nb.w); u.w = *(unsigned short*)&h;
            *(ushort4*)&xs[lr * XS_STR + c0] = u;
            *(ushort4*)&xn_out[base + c0] = u;
        }
    }
    __syncthreads();

    short8 aF[6];
    #pragma unroll
    for (int c = 0; c < 6; c++)
        aF[c] = (n15 < 8)
              ? *(const short8*)&xs[n15 * XS_STR + c * 32 + q * 8]
              : (short8){0, 0, 0, 0, 0, 0, 0, 0};

    for (int t = w; t < 12; t += 4) {        // 12 tiles = 192 cols
        float4v acc = (float4v){0.f, 0.f, 0.f, 0.f};
        #pragma unroll
        for (int c = 0; c < 6; c++) {
            const short8 bF = *(const short8*)&wP[(size_t)((t * 6 + c) * 64 + l) * 8];
            acc = __builtin_amdgcn_mfma_f32_16x16x32_bf16(aF[c], bF, acc, 0, 0, 0);
        }
        if (q < 2) {
            const int n0 = 16 * t;
            const float bb = bias[n0 + n15];
            #pragma unroll
            for (int r = 0; r < 4; r++)
                xp_out[(size_t)(p0 + 4 * q + r) * 192 + n0 + n15] = f2b(acc[r] + bb);
        }
    }
}

// ==== MEGA-FUSED: dwconv+LN+GELU + off/mask/cfs MFMA + softmax + bilinear
//      sampling + cfs blend (-> LDS) + out_proj + LN(rpn1)+res + LN(norm2)
//      + fc1+GELU + fc2 + LN(rpn2) + res.   16 px/block, 784 blocks.
__global__ __launch_bounds__(256) void sample_mlp_k(
        const bf16* __restrict__ xp, const bf16* __restrict__ xn,
        const float* __restrict__ dww, const float* __restrict__ dwb,
        const float* __restrict__ dwlnw, const float* __restrict__ dwlnb,
        const bf16* __restrict__ omP, const float* __restrict__ offb,
        const float* __restrict__ maskb, const float* __restrict__ cfsb,
        const bf16* __restrict__ wP, const float* __restrict__ bias,
        const float* __restrict__ x,
        const float* __restrict__ r1w, const float* __restrict__ r1b,
        const float* __restrict__ n2w, const float* __restrict__ n2b,
        const bf16* __restrict__ fc1P, const float* __restrict__ fc1b,
        const bf16* __restrict__ fc2P, const float* __restrict__ fc2b,
        const float* __restrict__ r2w, const float* __restrict__ r2b,
        float* __restrict__ out)
{
    __shared__ __align__(16) bf16 xs[16 * XS_STR];
    // union region, disjoint lifetimes:
    //   phase 0-1: cv[16][192] f32 (12288 B)
    //   phase 2-3: offs_l[16][193] (12352) + mls_l[16][97] (6208) + cfs[16][16] (1024)
    //   phase 4+ : h1[16][H1S] bf16 (24832 B)
    __shared__ __align__(16) char uni[16 * H1S * 2];
    __shared__ float ps[4][16], pq[4][16], ps2[4][16], pq2[4][16];

    float (*cv)[192]     = (float(*)[192])uni;
    float (*offs_l)[OFS] = (float(*)[OFS])uni;
    float (*mls_l)[MLS]  = (float(*)[MLS])(uni + 12352);
    float (*cfs_l)[16]   = (float(*)[16])(uni + 18560);
    bf16* h1             = (bf16*)uni;

    const int tid = threadIdx.x;
    const int w   = tid >> 6;
    const int l   = tid & 63;
    const int n15 = l & 15;
    const int q   = l >> 4;
    const int bid = (blockIdx.x & 7) * (NPIX / 128) + (blockIdx.x >> 3);
    const int p0  = bid * 16;

    // ---- phase 0: depthwise 3x3 conv, 16ch/item, 192 items, ONE pass -------
    if (tid < 192) {
        const int px  = tid / 12;
        const int ch0 = (tid - px * 12) * 16;
        const int pix = p0 + px;
        const int bimg = pix / (HH * WW);
        const int hw   = pix - bimg * (HH * WW);
        const int h    = hw / WW;
        const int wx   = hw - h * WW;
        const int ibase = bimg * (HH * WW * CC);

        float a[16];
        #pragma unroll
        for (int j = 0; j < 16; j += 4) {
            const float4 b4 = *(const float4*)&dwb[ch0 + j];
            a[j] = b4.x; a[j+1] = b4.y; a[j+2] = b4.z; a[j+3] = b4.w;
        }
        #pragma unroll
        for (int ky = 0; ky < 3; ky++) {
            const int yy = h + ky - 1;
            if (yy < 0 || yy >= HH) continue;
            #pragma unroll
            for (int kx = 0; kx < 3; kx++) {
                const int xx = wx + kx - 1;
                if (xx < 0 || xx >= WW) continue;
                const int o = ibase + (yy * WW + xx) * CC + ch0;
                const short8 v0 = *(const short8*)&xn[o];
                const short8 v1 = *(const short8*)&xn[o + 8];
                const int wo = (ky * 3 + kx) * CC + ch0;
                const float4 w0 = *(const float4*)&dww[wo];
                const float4 w1 = *(const float4*)&dww[wo + 4];
                const float4 w2 = *(const float4*)&dww[wo + 8];
                const float4 w3 = *(const float4*)&dww[wo + 12];
                a[0]  += b2fu(v0[0]) * w0.x; a[1]  += b2fu(v0[1]) * w0.y;
                a[2]  += b2fu(v0[2]) * w0.z; a[3]  += b2fu(v0[3]) * w0.w;
                a[4]  += b2fu(v0[4]) * w1.x; a[5]  += b2fu(v0[5]) * w1.y;
                a[6]  += b2fu(v0[6]) * w1.z; a[7]  += b2fu(v0[7]) * w1.w;
                a[8]  += b2fu(v1[0]) * w2.x; a[9]  += b2fu(v1[1]) * w2.y;
                a[10] += b2fu(v1[2]) * w2.z; a[11] += b2fu(v1[3]) * w2.w;
                a[12] += b2fu(v1[4]) * w3.x; a[13] += b2fu(v1[5]) * w3.y;
                a[14] += b2fu(v1[6]) * w3.z; a[15] += b2fu(v1[7]) * w3.w;
            }
        }
        #pragma unroll
        for (int j = 0; j < 16; j += 4)
            *(float4*)&cv[px][ch0 + j] = (float4){a[j], a[j+1], a[j+2], a[j+3]};
    }
    __syncthreads();

    // ---- phase 1: LN(1e-6) + GELU -> xs fragments (wave w -> px w+4*pass) --
    #pragma unroll
    for (int pass = 0; pass < 4; pass++) {
        const int px = w + 4 * pass;
        float v[3];
        #pragma unroll
        for (int i = 0; i < 3; i++) v[i] = cv[px][l + 64 * i];
        float s = v[0] + v[1] + v[2];
        float qq = v[0]*v[0] + v[1]*v[1] + v[2]*v[2];
        #pragma unroll
        for (int off = 32; off > 0; off >>= 1) {
            s  += __shfl_xor(s, off, 64);
            qq += __shfl_xor(qq, off, 64);
        }
        const float mu  = s * (1.f / CC);
        const float var = qq * (1.f / CC) - mu * mu;
        const float rs  = rsqrtf(var + 1e-6f);
        #pragma unroll
        for (int i = 0; i < 3; i++) {
            const int c = l + 64 * i;
            xs[px * XS_STR + c] = f2b(gelu_exact((v[i] - mu) * rs * dwlnw[c] + dwlnb[c]));
        }
    }
    __syncthreads();

    // ---- phase 2: off/mask/cfs MFMA (19 tiles, full 16 rows) + epilogues ---
    {
        short8 aF[6];
        #pragma unroll
        for (int c = 0; c < 6; c++)
            aF[c] = *(const short8*)&xs[n15 * XS_STR + c * 32 + q * 8];

        for (int t = w; t < 19; t += 4) {
            float4v acc = (float4v){0.f, 0.f, 0.f, 0.f};
            #pragma unroll
            for (int c = 0; c < 6; c++) {
                const short8 bF = *(const short8*)&omP[(size_t)((t * 6 + c) * 64 + l) * 8];
                acc = __builtin_amdgcn_mfma_f32_16x16x32_bf16(aF[c], bF, acc, 0, 0, 0);
            }
            if (t < 12) {
                const int n0 = 16 * t;
                const float bb = offb[n0 + n15];
                #pragma unroll
                for (int r = 0; r < 4; r++)
                    offs_l[4 * q + r][n0 + n15] = acc[r] + bb;
            } else if (t < 18) {
                // softmax over the 8 mask cols of each group = 8 adjacent
                // lanes (xor 1,2,4 stays inside the 8-lane n15 sub-group).
                const int m0 = 16 * t - 192;
                const float bb = maskb[m0 + n15];
                #pragma unroll
                for (int r = 0; r < 4; r++) {
                    const float vv = acc[r] + bb;
                    float mx = vv;
                    mx = fmaxf(mx, __shfl_xor(mx, 1, 64));
                    mx = fmaxf(mx, __shfl_xor(mx, 2, 64));
                    mx = fmaxf(mx, __shfl_xor(mx, 4, 64));
                    const float e = __expf(vv - mx);
                    float se = e;
                    se += __shfl_xor(se, 1, 64);
                    se += __shfl_xor(se, 2, 64);
                    se += __shfl_xor(se, 4, 64);
                    mls_l[4 * q + r][m0 + n15] = e * (1.f / se);
                }
            } else {
                const float bb = (n15 < 12) ? cfsb[n15] : 0.f;
                #pragma unroll
                for (int r = 0; r < 4; r++) {
                    const float cf = 1.f / (1.f + __expf(-(acc[r] + bb)));
                    if (n15 < 12) cfs_l[4 * q + r][n15] = cf;
                }
            }
        }
    }
    __syncthreads();

    // ---- phase 3: bilinear sampling + cfs blend -> xs, 192 items x 16ch ----
    if (tid < 192) {
        const int px  = tid / 12;
        const int g   = tid - px * 12;
        const int ch0 = g * 16;
        const int pix = p0 + px;
        const int bimg = pix / (HH * WW);
        const int hw   = pix - bimg * (HH * WW);
        const int h    = hw / WW;
        const int wxp  = hw - h * WW;
        const int ibase = bimg * (HH * WW * CC);

        const float cf = cfs_l[px][g];

        float acc[16];
        #pragma unroll
        for (int j = 0; j < 16; j++) acc[j] = 0.f;

        #pragma unroll 2
        for (int k = 0; k < 8; k++) {
            // grid point (remove_center): kk = k + (k>=4); gx = kk/3-1, gy = kk%3-1
            const int kk = k + (k >= 4 ? 1 : 0);
            const int gx = kk / 3 - 1;
            const int gy = kk - (kk / 3) * 3 - 1;
            const float mk  = mls_l[px][g * 8 + k];
            const float px_ = (float)(wxp + gx) + offs_l[px][g * 16 + 2 * k];
            const float py_ = (float)(h   + gy) + offs_l[px][g * 16 + 2 * k + 1];
            const float fx = floorf(px_), fy = floorf(py_);
            const float wxf = px_ - fx, wyf = py_ - fy;
            const int x0 = (int)fx, y0 = (int)fy;
            // branchless validity + clamped addresses
            const float vx0 = ((unsigned)x0       < WW) ? 1.f : 0.f;
            const float vx1 = ((unsigned)(x0 + 1) < WW) ? 1.f : 0.f;
            const float vy0 = ((unsigned)y0       < HH) ? 1.f : 0.f;
            const float vy1 = ((unsigned)(y0 + 1) < HH) ? 1.f : 0.f;
            const int x0c = min(max(x0, 0), WW - 1);
            const int x1c = min(max(x0 + 1, 0), WW - 1);
            const int y0c = min(max(y0, 0), HH - 1);
            const int y1c = min(max(y0 + 1, 0), HH - 1);
            const float wx0 = (1.f - wxf) * vx0, wx1 = wxf * vx1;
            const float wy0 = (1.f - wyf) * vy0, wy1 = wyf * vy1;
            const float w00 = mk * wy0 * wx0, w01 = mk * wy0 * wx1;
            const float w10 = mk * wy1 * wx0, w11 = mk * wy1 * wx1;
            const int r0 = ibase + y0c * (WW * CC) + ch0;
            const int r1 = ibase + y1c * (WW * CC) + ch0;
            const int o00 = r0 + x0c * CC, o01 = r0 + x1c * CC;
            const int o10 = r1 + x0c * CC, o11 = r1 + x1c * CC;
            const short8 a00 = *(const short8*)&xp[o00];
            const short8 b00 = *(const short8*)&xp[o00 + 8];
            const short8 a01 = *(const short8*)&xp[o01];
            const short8 b01 = *(const short8*)&xp[o01 + 8];
            const short8 a10 = *(const short8*)&xp[o10];
            const short8 b10 = *(const short8*)&xp[o10 + 8];
            const short8 a11 = *(const short8*)&xp[o11];
            const short8 b11 = *(const short8*)&xp[o11 + 8];
            #pragma unroll
            for (int j = 0; j < 8; j++) {
                acc[j]     += w00 * b2fu(a00[j]) + w01 * b2fu(a01[j])
                            + w10 * b2fu(a10[j]) + w11 * b2fu(a11[j]);
                acc[8 + j] += w00 * b2fu(b00[j]) + w01 * b2fu(b01[j])
                            + w10 * b2fu(b10[j]) + w11 * b2fu(b11[j]);
            }
        }

        const int po = pix * CC + ch0;
        const short8 xv0 = *(const short8*)&xp[po];
        const short8 xv1 = *(const short8*)&xp[po + 8];
        short8 o0, o1;
        #pragma unroll
        for (int j = 0; j < 8; j++) {
            const float v0 = acc[j]     * (1.f - cf) + b2fu(xv0[j]) * cf;
            const float v1 = acc[8 + j] * (1.f - cf) + b2fu(xv1[j]) * cf;
            bf16 hh;
            hh = f2b(v0); o0[j] = *(short*)&hh;
            hh = f2b(v1); o1[j] = *(short*)&hh;
        }
        *(short8*)&xs[px * XS_STR + ch0]     = o0;   // blended tile stays in LDS
        *(short8*)&xs[px * XS_STR + ch0 + 8] = o1;
    }
    __syncthreads();

    // ---- phase 4: out_proj MFMA + LN(rpn1)+res + LN(norm2) + fc1/gelu + fc2
    //      + LN(rpn2) + res  (identical math to the former gemm_ln2_mlp_k) ---
    {
        short8 aF[6];
        #pragma unroll
        for (int c = 0; c < 6; c++)
            aF[c] = *(const short8*)&xs[n15 * XS_STR + c * 32 + q * 8];

        float4v acc[3];
        #pragma unroll
        for (int t = 0; t < 3; t++) {
            const int tile = 3 * w + t;
            acc[t] = (float4v){0.f, 0.f, 0.f, 0.f};
            #pragma unroll
            for (int c = 0; c < 6; c++) {
                const short8 bF = *(const short8*)&wP[(size_t)((tile * 6 + c) * 64 + l) * 8];
                acc[t] = __builtin_amdgcn_mfma_f32_16x16x32_bf16(aF[c], bF, acc[t], 0, 0, 0);
            }
            const float bb = bias[16 * tile + n15];
            #pragma unroll
            for (int r = 0; r < 4; r++) acc[t][r] += bb;
        }

        #pragma unroll
        for (int r = 0; r < 4; r++) {
            float sp = acc[0][r] + acc[1][r] + acc[2][r];
            float qp = acc[0][r]*acc[0][r] + acc[1][r]*acc[1][r] + acc[2][r]*acc[2][r];
            #pragma unroll
            for (int o = 1; o < 16; o <<= 1) {
                sp += __shfl_xor(sp, o, 64);
                qp += __shfl_xor(qp, o, 64);
            }
            if (n15 == 0) { ps[w][4 * q + r] = sp; pq[w][4 * q + r] = qp; }
        }
        __syncthreads();

        float x2v[3][4];
        #pragma unroll
        for (int r = 0; r < 4; r++) {
            const int row = 4 * q + r;
            const float s  = ps[0][row] + ps[1][row] + ps[2][row] + ps[3][row];
            const float qq = pq[0][row] + pq[1][row] + pq[2][row] + pq[3][row];
            const float mu  = s * (1.f / CC);
            const float var = qq * (1.f / CC) - mu * mu;
            const float rs  = rsqrtf(var + 1e-5f);
            const size_t grow = p0 + row;
            #pragma unroll
            for (int t = 0; t < 3; t++) {
                const int col = 48 * w + 16 * t + n15;
                x2v[t][r] = x[grow * CC + col] + (acc[t][r] - mu) * rs * r1w[col] + r1b[col];
            }
        }
        #pragma unroll
        for (int r = 0; r < 4; r++) {
            float sp = x2v[0][r] + x2v[1][r] + x2v[2][r];
            float qp = x2v[0][r]*x2v[0][r] + x2v[1][r]*x2v[1][r] + x2v[2][r]*x2v[2][r];
            #pragma unroll
            for (int o = 1; o < 16; o <<= 1) {
                sp += __shfl_xor(sp, o, 64);
                qp += __shfl_xor(qp, o, 64);
            }
            if (n15 == 0) { ps2[w][4 * q + r] = sp; pq2[w][4 * q + r] = qp; }
        }
        __syncthreads();

        #pragma unroll
        for (int r = 0; r < 4; r++) {
            const int row = 4 * q + r;
            const float s  = ps2[0][row] + ps2[1][row] + ps2[2][row] + ps2[3][row];
            const float qq = pq2[0][row] + pq2[1][row] + pq2[2][row] + pq2[3][row];
            const float mu  = s * (1.f / CC);
            const float var = qq * (1.f / CC) - mu * mu;
            const float rs  = rsqrtf(var + 1e-5f);
            #pragma unroll
            for (int t = 0; t < 3; t++) {
                const int col = 48 * w + 16 * t + n15;
                xs[row * XS_STR + col] = f2b((x2v[t][r] - mu) * rs * n2w[col] + n2b[col]);
            }
        }
        __syncthreads();

        short8 aF2[6];
        #pragma unroll
        for (int c = 0; c < 6; c++)
            aF2[c] = *(const short8*)&xs[n15 * XS_STR + c * 32 + q * 8];

        #pragma unroll
        for (int t1 = 0; t1 < 12; t1++) {
            const int tile = 12 * w + t1;
            float4v a1 = (float4v){0.f, 0.f, 0.f, 0.f};
            #pragma unroll
            for (int c = 0; c < 6; c++) {
                const short8 bF = *(const short8*)&fc1P[(size_t)((tile * 6 + c) * 64 + l) * 8];
                a1 = __builtin_amdgcn_mfma_f32_16x16x32_bf16(aF2[c], bF, a1, 0, 0, 0);
            }
            const int n0 = 16 * tile;
            const float bb = fc1b[n0 + n15];
            #pragma unroll
            for (int r = 0; r < 4; r++)
                h1[(4 * q + r) * H1S + n0 + n15] = f2b(gelu_exact(a1[r] + bb));
        }
        __syncthreads();

        float4v acc2[3];
        #pragma unroll
        for (int t = 0; t < 3; t++) acc2[t] = (float4v){0.f, 0.f, 0.f, 0.f};
        #pragma unroll 4
        for (int kc = 0; kc < 24; kc++) {
            const short8 a2 = *(const short8*)&h1[n15 * H1S + kc * 32 + q * 8];
            #pragma unroll
            for (int t = 0; t < 3; t++) {
                const int tile = 3 * w + t;
                const short8 bF = *(const short8*)&fc2P[(size_t)((tile * 24 + kc) * 64 + l) * 8];
                acc2[t] = __builtin_amdgcn_mfma_f32_16x16x32_bf16(a2, bF, acc2[t], 0, 0, 0);
            }
        }
        #pragma unroll
        for (int t = 0; t < 3; t++) {
            const float bb = fc2b[48 * w + 16 * t + n15];
            #pragma unroll
            for (int r = 0; r < 4; r++) acc2[t][r] += bb;
        }

        #pragma unroll
        for (int r = 0; r < 4; r++) {
            float sp = acc2[0][r] + acc2[1][r] + acc2[2][r];
            float qp = acc2[0][r]*acc2[0][r] + acc2[1][r]*acc2[1][r] + acc2[2][r]*acc2[2][r];
            #pragma unroll
            for (int o = 1; o < 16; o <<= 1) {
                sp += __shfl_xor(sp, o, 64);
                qp += __shfl_xor(qp, o, 64);
            }
            if (n15 == 0) { ps[w][4 * q + r] = sp; pq[w][4 * q + r] = qp; }
        }
        __syncthreads();

        #pragma unroll
        for (int r = 0; r < 4; r++) {
            const int row = 4 * q + r;
            const float s  = ps[0][row] + ps[1][row] + ps[2][row] + ps[3][row];
            const float qq = pq[0][row] + pq[1][row] + pq[2][row] + pq[3][row];
            const float mu  = s * (1.f / CC);
            const float var = qq * (1.f / CC) - mu * mu;
            const float rs  = rsqrtf(var + 1e-5f);
            const size_t grow = p0 + row;
            #pragma unroll
            for (int t = 0; t < 3; t++) {
                const int col = 48 * w + 16 * t + n15;
                out[grow * CC + col] = x2v[t][r]
                                     + (acc2[t][r] - mu) * rs * r2w[col] + r2b[col];
            }
        }
    }
}

extern "C" void kernel_launch(void* const* d_in, const int* in_sizes, int n_in,
                              void* d_out, int out_size, void* d_ws, size_t ws_size,
                              hipStream_t stream) {
    const float* x      = (const float*)d_in[0];
    const float* n1w    = (const float*)d_in[1];
    const float* n1b    = (const float*)d_in[2];
    const float* n2w    = (const float*)d_in[3];
    const float* n2b    = (const float*)d_in[4];
    const float* rpn1w  = (const float*)d_in[5];
    const float* rpn1b  = (const float*)d_in[6];
    const float* rpn2w  = (const float*)d_in[7];
    const float* rpn2b  = (const float*)d_in[8];
    const float* inpw   = (const float*)d_in[9];
    const float* inpb   = (const float*)d_in[10];
    const float* dww    = (const float*)d_in[11];
    const float* dwb    = (const float*)d_in[12];
    const float* dwlnw  = (const float*)d_in[13];
    const float* dwlnb  = (const float*)d_in[14];
    const float* offw   = (const float*)d_in[15];
    const float* offb   = (const float*)d_in[16];
    const float* maskw  = (const float*)d_in[17];
    const float* maskb  = (const float*)d_in[18];
    const float* cfsw   = (const float*)d_in[19];
    const float* cfsb   = (const float*)d_in[20];
    const float* outpw  = (const float*)d_in[21];
    const float* outpb  = (const float*)d_in[22];
    const float* fc1w   = (const float*)d_in[23];
    const float* fc1b   = (const float*)d_in[24];
    const float* fc2w   = (const float*)d_in[25];
    const float* fc2b   = (const float*)d_in[26];

    const int N = NPIX;                       // 12544
    const size_t NP = (size_t)N * CC;
    bf16* B0  = (bf16*)d_ws;                  // xn
    bf16* B1  = B0 + NP;                      // xp
    bf16* wsB = B1 + NP;                      // packed bf16 weights
    const bf16* inpP = wsB;
    const bf16* omP  = wsB + 36864;           // 19 tiles (off+mask+cfs)
    const bf16* outP = wsB + 95232;
    const bf16* fc1P = wsB + 132096;
    const bf16* fc2P = wsB + 279552;

    const int g16 = N / 16;    // 784

    // 0. weight prep (bf16, fragment-packed; cfs_w folded into om pack)
    prep_w_k<<<576, 256, 0, stream>>>(inpw, offw, maskw, cfsw, outpw, fc1w, fc2w, wsB);
    // 1. FUSED xn = LN(x); xp = xn @ in_proj + b   (8px, 1568 blocks) -> B0, B1
    ln_gemm8_k<<<N / 8, 256, 0, stream>>>(x, n1w, n1b, inpP, inpb, B0, B1);
    // 2. MEGA-FUSED dwconv+off/mask GEMM+sampling+blend+out_proj+MLP (16px) -> d_out
    sample_mlp_k<<<g16, 256, 0, stream>>>(B1, B0, dww, dwb, dwlnw, dwlnb,
                                          omP, offb, maskb, cfsb,
                                          outP, outpb, x, rpn1w, rpn1b,
                                          n2w, n2b, fc1P, fc1b, fc2P, fc2b,
                                          rpn2w, rpn2b, (float*)d_out);
}